// Round 2
// baseline (135.082 us; speedup 1.0000x reference)
//
#include <hip/hip_runtime.h>
#include <hip/hip_bf16.h>

#define NROW 8192   // B*A = 64*128
#define INC  128
#define OUTC 64
#define BG   16     // key-split factor: grid 1024 -> 4 blocks/CU

// Q is pre-scaled by log2(e)/sqrt(64) at projection time, so attention
// computes p = exp2(q'.k) with a single v_exp_f32 per score.
#define QSCALE 0.18033688011112042f

typedef __bf16 bf16x8 __attribute__((ext_vector_type(8)));
typedef __bf16 bf16x4 __attribute__((ext_vector_type(4)));
typedef short  s16x4  __attribute__((ext_vector_type(4)));
typedef float  f32x4  __attribute__((ext_vector_type(4)));

static __device__ __forceinline__ f32x4 mfma16(bf16x8 a, bf16x8 b, f32x4 c) {
    return __builtin_amdgcn_mfma_f32_16x16x32_bf16(a, b, c, 0, 0, 0);
}
// 16x16x16 bf16 (K=16). C/D of S^T IS the A-operand layout of P for PV.
static __device__ __forceinline__ f32x4 mfma1k(s16x4 a, s16x4 b, f32x4 c) {
    return __builtin_amdgcn_mfma_f32_16x16x16bf16_1k(a, b, c, 0, 0, 0);
}

static __device__ __forceinline__ bf16x8 cvt8(float4 lo, float4 hi) {
    bf16x8 r;
    r[0] = (__bf16)lo.x; r[1] = (__bf16)lo.y; r[2] = (__bf16)lo.z; r[3] = (__bf16)lo.w;
    r[4] = (__bf16)hi.x; r[5] = (__bf16)hi.y; r[6] = (__bf16)hi.z; r[7] = (__bf16)hi.w;
    return r;
}

// ---------------------------------------------------------------------------
// Kernel 1: projection via MFMA. grid = 768 = mat(3) x b(64) x aq(4).
// Q/K/V written in FRAGMENT-TILED layout (512-B 16x16 tiles), Q pre-scaled.
// Also zeroes the Oacc/lacc accumulators (graph dependency orders this
// before attn's atomics) -> no separate memset dispatch.
__global__ __launch_bounds__(256) void proj_kernel(
    const float* __restrict__ feat,
    const float* __restrict__ Wq, const float* __restrict__ bq,
    const float* __restrict__ Wk, const float* __restrict__ bk,
    const float* __restrict__ Wv, const float* __restrict__ bv,
    __hip_bfloat16* __restrict__ qbf, __hip_bfloat16* __restrict__ kbf,
    __hip_bfloat16* __restrict__ vbf, __hip_bfloat16* __restrict__ vnb,
    float* __restrict__ Oacc /* 2MB Oacc + 32KB lacc, contiguous */)
{
    __shared__ float slab[32 * 132];
    __shared__ float vbuf[32 * 66];
    __shared__ float invb[32];

    const int blk = blockIdx.x;

    // zero Oacc (8192x64 f32) + lacc (8192 f32) = 133120 float4s
    {
        const int zi = blk * 256 + threadIdx.x;
        if (zi < 133120)
            ((float4*)Oacc)[zi] = (float4){0.f, 0.f, 0.f, 0.f};
    }

    const int mat = blk >> 8;
    const int b   = (blk >> 2) & 63;
    const int a0  = (blk & 3) * 32;
    const int r0  = b * 128 + a0;
    const float* fb = feat + (size_t)b * INC * 128;

    for (int i = threadIdx.x; i < 32 * 128; i += 256) {
        int c = i >> 5, a = i & 31;
        slab[a * 132 + c] = fb[c * 128 + a0 + a];
    }
    __syncthreads();

    const int w    = threadIdx.x >> 6;
    const int lane = threadIdx.x & 63;
    const int l16  = lane & 15;
    const int quad = lane >> 4;
    const int n0   = w * 16;

    const float* W    = (mat == 0) ? Wq : (mat == 1) ? Wk : Wv;
    const float* bias = (mat == 0) ? bq : (mat == 1) ? bk : bv;

    f32x4 acc[2] = {{0.f,0.f,0.f,0.f},{0.f,0.f,0.f,0.f}};
    #pragma unroll
    for (int kc = 0; kc < 4; ++kc) {
        const int k0 = kc * 32 + quad * 8;
        const float* wr = W + (n0 + l16) * INC + k0;
        bf16x8 bfr = cvt8(*(const float4*)wr, *(const float4*)(wr + 4));
        #pragma unroll
        for (int u = 0; u < 2; ++u) {
            const float* ar = slab + (u * 16 + l16) * 132 + k0;
            bf16x8 afr = cvt8(*(const float4*)ar, *(const float4*)(ar + 4));
            acc[u] = mfma16(afr, bfr, acc[u]);
        }
    }
    const float bl = bias[n0 + l16];
    const float sc = (mat == 0) ? QSCALE : 1.0f;

    if (mat < 2) {
        __hip_bfloat16* dst = mat ? kbf : qbf;
        #pragma unroll
        for (int u = 0; u < 2; ++u) {
            const int base = ((((r0 >> 4) + u) * 4 + w) << 8) + l16;
            #pragma unroll
            for (int r = 0; r < 4; ++r)
                dst[base + (quad * 4 + r) * 16] = __float2bfloat16((acc[u][r] + bl) * sc);
        }
    } else {
        #pragma unroll
        for (int u = 0; u < 2; ++u)
            #pragma unroll
            for (int r = 0; r < 4; ++r)
                vbuf[(u * 16 + quad * 4 + r) * 66 + n0 + l16] = acc[u][r] + bl;
        __syncthreads();
        const int rl = threadIdx.x >> 3;
        const int jj = threadIdx.x & 7;
        float ss = 0.f;
        #pragma unroll
        for (int i = 0; i < 8; ++i) {
            float x = vbuf[rl * 66 + jj * 8 + i];
            ss += x * x;
        }
        ss += __shfl_xor(ss, 1, 64);
        ss += __shfl_xor(ss, 2, 64);
        ss += __shfl_xor(ss, 4, 64);
        if (jj == 0) invb[rl] = rsqrtf(fmaxf(ss, 1e-24f));
        __syncthreads();
        float inv = invb[rl];
        bf16x8 vp;
        #pragma unroll
        for (int i = 0; i < 8; ++i)
            vp[i] = (__bf16)(vbuf[rl * 66 + jj * 8 + i] * inv);
        *(bf16x8*)(vnb + (size_t)(r0 + rl) * 64 + jj * 8) = vp;
        const int tl = threadIdx.x & 15;
        const int n  = (threadIdx.x >> 4) & 3;
        const int s_ = threadIdx.x >> 6;
        bf16x8 pack;
        #pragma unroll
        for (int j = 0; j < 8; ++j) {
            int key = s_ * 8 + j;
            pack[j] = (__bf16)(vbuf[key * 66 + n * 16 + tl] * invb[key]);
        }
        const int base = ((((r0 >> 4) + (s_ >> 1)) * 4 + n) << 8) + tl * 16 + (s_ & 1) * 8;
        *(bf16x8*)(vbf + base) = pack;
    }
}

// ---------------------------------------------------------------------------
// Kernel 2: attention. grid = 1024 = qb(64) x bg(16); block = 128 q-rows x
// 512 keys; 4 blocks/CU = 4 waves/SIMD. Epilogue: atomicAdd partial O and l
// into 2MB Oacc / 32KB lacc (16-way contention per address, spread in time)
// -> replaces the 32MB Opart write + 32MB combine read. Block 0 also zeroes
// the 16KB output (graph dependency orders it before sim's atomics).
__global__ __launch_bounds__(256, 4) void attn_kernel(
    const __hip_bfloat16* __restrict__ qbf,
    const __hip_bfloat16* __restrict__ kbf,
    const __hip_bfloat16* __restrict__ vbf,
    float* __restrict__ Oacc, float* __restrict__ lacc,
    float* __restrict__ outz)
{
    if (blockIdx.x == 0) {
        #pragma unroll
        for (int z = 0; z < 4; ++z)
            ((float4*)outz)[threadIdx.x * 4 + z] = (float4){0.f, 0.f, 0.f, 0.f};
    }

    const int qb    = blockIdx.x >> 4;
    const int bg    = blockIdx.x & 15;
    const int w     = threadIdx.x >> 6;
    const int lane  = threadIdx.x & 63;
    const int l16   = lane & 15;
    const int quad  = lane >> 4;
    const int r0    = qb * 128 + w * 32;
    const int fo    = l16 * 16 + quad * 4;            // K=16 frag elem offset
    const int fo32  = l16 * 16 + (quad & 1) * 8;      // K=32 frag elem offset
    const int qh    = quad >> 1;                      // K=32 tile-pair half

    // Q fragments in K=32 form
    bf16x8 qf32[2][2];
    #pragma unroll
    for (int u = 0; u < 2; ++u)
        #pragma unroll
        for (int p = 0; p < 2; ++p)
            qf32[u][p] = *(const bf16x8*)(qbf +
                ((((r0 >> 4) + u) * 4 + p * 2 + qh) << 8) + fo32);

    f32x4 of[2][4];
    float lp[2] = {0.f, 0.f};
    #pragma unroll
    for (int u = 0; u < 2; ++u)
        #pragma unroll
        for (int n = 0; n < 4; ++n)
            of[u][n] = (f32x4){0.f, 0.f, 0.f, 0.f};

    // byte pointers: chunk stride 2048 B, iteration (2 chunks) stride 4096 B
    const int ck0 = bg * 32;                          // 32 chunks = 512 keys
    const char* kp = (const char*)kbf + ck0 * 2048 + qh * 512 + fo32 * 2;
    const char* vp = (const char*)vbf + ck0 * 2048 + fo * 2;

    bf16x8 kfA[2][2], kfB[2][2];
    #pragma unroll
    for (int h = 0; h < 2; ++h)
        #pragma unroll
        for (int p = 0; p < 2; ++p)
            kfA[h][p] = *(const bf16x8*)(kp + h * 2048 + p * 1024);
    kp += 4096;

    #pragma unroll 1
    for (int body = 0; body < 8; ++body) {
        #pragma unroll
        for (int st = 0; st < 2; ++st) {
            bf16x8 (&kf)[2][2] = (st == 0) ? kfA : kfB;
            bf16x8 (&kn)[2][2] = (st == 0) ? kfB : kfA;
            // V frags (K=16 form), immediate offsets
            s16x4 vf[4][2];
            #pragma unroll
            for (int n = 0; n < 4; ++n)
                #pragma unroll
                for (int h = 0; h < 2; ++h)
                    vf[n][h] = *(const s16x4*)(vp + h * 2048 + n * 512);
            // prefetch next iteration's K (stray read past range is harmless)
            #pragma unroll
            for (int h = 0; h < 2; ++h)
                #pragma unroll
                for (int p = 0; p < 2; ++p)
                    kn[h][p] = *(const bf16x8*)(kp + h * 2048 + p * 1024);
            vp += 4096;
            kp += 4096;

            const f32x4 zero = (f32x4){0.f, 0.f, 0.f, 0.f};
            #pragma unroll
            for (int u = 0; u < 2; ++u) {
                f32x4 s0 = mfma16(kf[0][0], qf32[u][0], zero);
                s0       = mfma16(kf[0][1], qf32[u][1], s0);
                f32x4 s1 = mfma16(kf[1][0], qf32[u][0], zero);
                s1       = mfma16(kf[1][1], qf32[u][1], s1);
                union { bf16x4 v; s16x4 s; } pf0, pf1;
                #pragma unroll
                for (int r = 0; r < 4; ++r) {
                    float p0 = __builtin_amdgcn_exp2f(s0[r]);   // raw v_exp_f32
                    float p1 = __builtin_amdgcn_exp2f(s1[r]);
                    lp[0 + u] += p0 + p1;
                    pf0.v[r] = (__bf16)p0;
                    pf1.v[r] = (__bf16)p1;
                }
                #pragma unroll
                for (int n = 0; n < 4; ++n) {
                    of[u][n] = mfma1k(pf0.s, vf[n][0], of[u][n]);
                    of[u][n] = mfma1k(pf1.s, vf[n][1], of[u][n]);
                }
            }
        }
    }

    // per-wave l reduction across quads
    #pragma unroll
    for (int u = 0; u < 2; ++u) {
        float v = lp[u];
        v += __shfl_xor(v, 16, 64);
        v += __shfl_xor(v, 32, 64);
        lp[u] = v;
    }

    // atomic accumulation: rows [r0, r0+32) of Oacc / lacc
    #pragma unroll
    for (int u = 0; u < 2; ++u)
        #pragma unroll
        for (int n = 0; n < 4; ++n)
            #pragma unroll
            for (int r = 0; r < 4; ++r)
                atomicAdd(&Oacc[(size_t)(r0 + u * 16 + quad * 4 + r) * 64 + n * 16 + l16],
                          of[u][n][r]);
    if (quad == 0) {
        atomicAdd(&lacc[r0 + l16],      lp[0]);
        atomicAdd(&lacc[r0 + 16 + l16], lp[1]);
    }
}

// ---------------------------------------------------------------------------
// Kernel 3: fused normalize + sim GEMM. grid = 32 blocks x 256 thr.
// Block bk covers k-range [bk*256, bk*256+256) of the 8192-long contraction
// (k = a*64 + d) -> needs exactly the 256 rows {(b, a0+j) : b<64, j<4},
// a0 = bk*4. Phase 1: normalize those rows (divide by lacc, l2-normalize)
// into LDS (row stride padded to 264 bf16 -> 2-way banks, free). Phase 2:
// split-K MFMA GEMM vs vnb, atomicAdd into out.
__global__ __launch_bounds__(256) void sim_kernel(
    const __hip_bfloat16* __restrict__ vnb,
    const float* __restrict__ Oacc, const float* __restrict__ lacc,
    float* __restrict__ out)
{
    __shared__ __hip_bfloat16 qn[64][264];

    const int a0 = blockIdx.x * 4;
    // ---- phase 1: thread i normalizes row (b = i>>2, a = a0 + (i&3)) ----
    {
        const int i   = threadIdx.x;
        const int b   = i >> 2, j = i & 3;
        const int row = b * 128 + a0 + j;
        const float4* Or = (const float4*)(Oacc + (size_t)row * 64);
        const float inv_l = 1.0f / lacc[row];
        float4 v[16];
        float ss = 0.f;
        #pragma unroll
        for (int c4 = 0; c4 < 16; ++c4) {
            float4 t = Or[c4];
            t.x *= inv_l; t.y *= inv_l; t.z *= inv_l; t.w *= inv_l;
            ss += t.x * t.x + t.y * t.y + t.z * t.z + t.w * t.w;
            v[c4] = t;
        }
        const float inv = rsqrtf(fmaxf(ss, 1e-24f));
        #pragma unroll
        for (int c4 = 0; c4 < 16; ++c4) {
            v[c4].x *= inv; v[c4].y *= inv; v[c4].z *= inv; v[c4].w *= inv;
        }
        #pragma unroll
        for (int m = 0; m < 8; ++m)
            *(bf16x8*)&qn[b][j * 64 + m * 8] = cvt8(v[2 * m], v[2 * m + 1]);
    }
    __syncthreads();

    // ---- phase 2: GEMM. 4 waves x 2 k-slices of this block's 256-k range --
    const int w    = threadIdx.x >> 6;
    const int lane = threadIdx.x & 63;
    const int l16  = lane & 15;
    const int quad = lane >> 4;
    const int kblk = blockIdx.x * 256;

    f32x4 acc[4][4];
    #pragma unroll
    for (int mi = 0; mi < 4; ++mi)
        #pragma unroll
        for (int ni = 0; ni < 4; ++ni)
            acc[mi][ni] = (f32x4){0.f, 0.f, 0.f, 0.f};

    #pragma unroll
    for (int s = 0; s < 2; ++s) {
        const int k0 = (w * 2 + s) * 32 + quad * 8;   // local k in [0,256)
        bf16x8 af[4], bfv[4];
        #pragma unroll
        for (int mi = 0; mi < 4; ++mi)
            af[mi] = *(const bf16x8*)(vnb + (size_t)(mi * 16 + l16) * 8192 + kblk + k0);
        #pragma unroll
        for (int ni = 0; ni < 4; ++ni)
            bfv[ni] = *(const bf16x8*)&qn[ni * 16 + l16][k0];
        #pragma unroll
        for (int mi = 0; mi < 4; ++mi)
            #pragma unroll
            for (int ni = 0; ni < 4; ++ni)
                acc[mi][ni] = mfma16(af[mi], bfv[ni], acc[mi][ni]);
    }

    #pragma unroll
    for (int mi = 0; mi < 4; ++mi)
        #pragma unroll
        for (int ni = 0; ni < 4; ++ni)
            #pragma unroll
            for (int r = 0; r < 4; ++r)
                atomicAdd(&out[(mi * 16 + quad * 4 + r) * 64 + ni * 16 + l16],
                          acc[mi][ni][r] * (1.f / 128.f));
}

// ---------------------------------------------------------------------------
extern "C" void kernel_launch(void* const* d_in, const int* in_sizes, int n_in,
                              void* d_out, int out_size, void* d_ws, size_t ws_size,
                              hipStream_t stream)
{
    const float* feat = (const float*)d_in[0];
    const float* Wq   = (const float*)d_in[1];
    const float* bq   = (const float*)d_in[2];
    const float* Wk   = (const float*)d_in[3];
    const float* bk   = (const float*)d_in[4];
    const float* Wv   = (const float*)d_in[5];
    const float* bv   = (const float*)d_in[6];
    float* out = (float*)d_out;

    const size_t MB = 1u << 20;
    char* ws = (char*)d_ws;
    __hip_bfloat16* qbf = (__hip_bfloat16*)(ws);              // 1 MB (frag-tiled, pre-scaled)
    __hip_bfloat16* kbf = (__hip_bfloat16*)(ws + 1 * MB);     // 1 MB (frag-tiled)
    __hip_bfloat16* vbf = (__hip_bfloat16*)(ws + 2 * MB);     // 1 MB (frag-tiled)
    __hip_bfloat16* vnb = (__hip_bfloat16*)(ws + 3 * MB);     // 1 MB (row-major)
    float* Oacc = (float*)(ws + 4 * MB);                      // 2 MB (8192 x 64 f32)
    float* lacc = (float*)(ws + 6 * MB);                      // 32 KB (8192 f32), contiguous after Oacc

    proj_kernel<<<768, 256, 0, stream>>>(feat, Wq, bq, Wk, bk, Wv, bv,
                                         qbf, kbf, vbf, vnb, Oacc);
    attn_kernel<<<1024, 256, 0, stream>>>(qbf, kbf, vbf, Oacc, lacc, out);
    sim_kernel<<<32, 256, 0, stream>>>(vnb, Oacc, lacc, out);
}

// Round 3
// 134.452 us; speedup vs baseline: 1.0047x; 1.0047x over previous
//
#include <hip/hip_runtime.h>
#include <hip/hip_bf16.h>

#define NROW 8192   // B*A = 64*128
#define INC  128
#define OUTC 64
#define BG   16     // key-split factor: grid 1024 -> 4 blocks/CU

// Q is pre-scaled by log2(e)/sqrt(64) at projection time, so attention
// computes p = exp2(q'.k) with a single v_exp_f32 per score.
#define QSCALE 0.18033688011112042f

typedef __bf16 bf16x8 __attribute__((ext_vector_type(8)));
typedef __bf16 bf16x4 __attribute__((ext_vector_type(4)));
typedef short  s16x4  __attribute__((ext_vector_type(4)));
typedef float  f32x4  __attribute__((ext_vector_type(4)));

static __device__ __forceinline__ f32x4 mfma16(bf16x8 a, bf16x8 b, f32x4 c) {
    return __builtin_amdgcn_mfma_f32_16x16x32_bf16(a, b, c, 0, 0, 0);
}
// 16x16x16 bf16 (K=16). C/D of S^T IS the A-operand layout of P for PV.
static __device__ __forceinline__ f32x4 mfma1k(s16x4 a, s16x4 b, f32x4 c) {
    return __builtin_amdgcn_mfma_f32_16x16x16bf16_1k(a, b, c, 0, 0, 0);
}

static __device__ __forceinline__ bf16x8 cvt8(float4 lo, float4 hi) {
    bf16x8 r;
    r[0] = (__bf16)lo.x; r[1] = (__bf16)lo.y; r[2] = (__bf16)lo.z; r[3] = (__bf16)lo.w;
    r[4] = (__bf16)hi.x; r[5] = (__bf16)hi.y; r[6] = (__bf16)hi.z; r[7] = (__bf16)hi.w;
    return r;
}

// ---------------------------------------------------------------------------
// Kernel 1: projection via MFMA. grid = 768 = mat(3) x b(64) x aq(4).
// Q/K/V written in FRAGMENT-TILED layout (512-B 16x16 tiles), Q pre-scaled.
// Also zeroes the Oacc/lacc accumulators (graph dependency orders this
// before attn's atomics) -> no separate memset dispatch.
__global__ __launch_bounds__(256) void proj_kernel(
    const float* __restrict__ feat,
    const float* __restrict__ Wq, const float* __restrict__ bq,
    const float* __restrict__ Wk, const float* __restrict__ bk,
    const float* __restrict__ Wv, const float* __restrict__ bv,
    __hip_bfloat16* __restrict__ qbf, __hip_bfloat16* __restrict__ kbf,
    __hip_bfloat16* __restrict__ vbf, __hip_bfloat16* __restrict__ vnb,
    float* __restrict__ Oacc /* 2MB Oacc + 32KB lacc, contiguous */)
{
    __shared__ float slab[32 * 132];
    __shared__ float vbuf[32 * 66];
    __shared__ float invb[32];

    const int blk = blockIdx.x;

    // zero Oacc (8192x64 f32) + lacc (8192 f32) = 133120 float4s
    {
        const int zi = blk * 256 + threadIdx.x;
        if (zi < 133120)
            ((float4*)Oacc)[zi] = (float4){0.f, 0.f, 0.f, 0.f};
    }

    const int mat = blk >> 8;
    const int b   = (blk >> 2) & 63;
    const int a0  = (blk & 3) * 32;
    const int r0  = b * 128 + a0;
    const float* fb = feat + (size_t)b * INC * 128;

    for (int i = threadIdx.x; i < 32 * 128; i += 256) {
        int c = i >> 5, a = i & 31;
        slab[a * 132 + c] = fb[c * 128 + a0 + a];
    }
    __syncthreads();

    const int w    = threadIdx.x >> 6;
    const int lane = threadIdx.x & 63;
    const int l16  = lane & 15;
    const int quad = lane >> 4;
    const int n0   = w * 16;

    const float* W    = (mat == 0) ? Wq : (mat == 1) ? Wk : Wv;
    const float* bias = (mat == 0) ? bq : (mat == 1) ? bk : bv;

    f32x4 acc[2] = {{0.f,0.f,0.f,0.f},{0.f,0.f,0.f,0.f}};
    #pragma unroll
    for (int kc = 0; kc < 4; ++kc) {
        const int k0 = kc * 32 + quad * 8;
        const float* wr = W + (n0 + l16) * INC + k0;
        bf16x8 bfr = cvt8(*(const float4*)wr, *(const float4*)(wr + 4));
        #pragma unroll
        for (int u = 0; u < 2; ++u) {
            const float* ar = slab + (u * 16 + l16) * 132 + k0;
            bf16x8 afr = cvt8(*(const float4*)ar, *(const float4*)(ar + 4));
            acc[u] = mfma16(afr, bfr, acc[u]);
        }
    }
    const float bl = bias[n0 + l16];
    const float sc = (mat == 0) ? QSCALE : 1.0f;

    if (mat < 2) {
        __hip_bfloat16* dst = mat ? kbf : qbf;
        #pragma unroll
        for (int u = 0; u < 2; ++u) {
            const int base = ((((r0 >> 4) + u) * 4 + w) << 8) + l16;
            #pragma unroll
            for (int r = 0; r < 4; ++r)
                dst[base + (quad * 4 + r) * 16] = __float2bfloat16((acc[u][r] + bl) * sc);
        }
    } else {
        #pragma unroll
        for (int u = 0; u < 2; ++u)
            #pragma unroll
            for (int r = 0; r < 4; ++r)
                vbuf[(u * 16 + quad * 4 + r) * 66 + n0 + l16] = acc[u][r] + bl;
        __syncthreads();
        const int rl = threadIdx.x >> 3;
        const int jj = threadIdx.x & 7;
        float ss = 0.f;
        #pragma unroll
        for (int i = 0; i < 8; ++i) {
            float x = vbuf[rl * 66 + jj * 8 + i];
            ss += x * x;
        }
        ss += __shfl_xor(ss, 1, 64);
        ss += __shfl_xor(ss, 2, 64);
        ss += __shfl_xor(ss, 4, 64);
        if (jj == 0) invb[rl] = rsqrtf(fmaxf(ss, 1e-24f));
        __syncthreads();
        float inv = invb[rl];
        bf16x8 vp;
        #pragma unroll
        for (int i = 0; i < 8; ++i)
            vp[i] = (__bf16)(vbuf[rl * 66 + jj * 8 + i] * inv);
        *(bf16x8*)(vnb + (size_t)(r0 + rl) * 64 + jj * 8) = vp;
        const int tl = threadIdx.x & 15;
        const int n  = (threadIdx.x >> 4) & 3;
        const int s_ = threadIdx.x >> 6;
        bf16x8 pack;
        #pragma unroll
        for (int j = 0; j < 8; ++j) {
            int key = s_ * 8 + j;
            pack[j] = (__bf16)(vbuf[key * 66 + n * 16 + tl] * invb[key]);
        }
        const int base = ((((r0 >> 4) + (s_ >> 1)) * 4 + n) << 8) + tl * 16 + (s_ & 1) * 8;
        *(bf16x8*)(vbf + base) = pack;
    }
}

// ---------------------------------------------------------------------------
// Kernel 2: attention. grid = 1024 = qb(64) x bg(16); block = 128 q-rows x
// 512 keys; 4 blocks/CU = 4 waves/SIMD.
//
// REGISTER RESIDENCY FIX (round 3): the previous double-buffer used
//   bf16x8 (&kf)[2][2] = (st==0) ? kfA : kfB;
// which takes the arrays' addresses, defeats SROA, and demoted ~50 regs of
// fragments to scratch (VGPR_Count=56 vs ~108 live -> ~1.9GB of L2 spill
// traffic ~= the whole 54us runtime). Now: individually named K fragments,
// explicit 2x-unrolled macro body, V frags as named locals. of[][]/qf32[][]
// keep constant-only indices (SROA-safe).
#define ATTN_ITER(K00,K01,K10,K11, N00,N01,N10,N11)                          \
    do {                                                                     \
        s16x4 v00 = *(const s16x4*)(vp);                                     \
        s16x4 v01 = *(const s16x4*)(vp + 512);                               \
        s16x4 v02 = *(const s16x4*)(vp + 1024);                              \
        s16x4 v03 = *(const s16x4*)(vp + 1536);                              \
        s16x4 v10 = *(const s16x4*)(vp + 2048);                              \
        s16x4 v11 = *(const s16x4*)(vp + 2560);                              \
        s16x4 v12 = *(const s16x4*)(vp + 3072);                              \
        s16x4 v13 = *(const s16x4*)(vp + 3584);                              \
        N00 = *(const bf16x8*)(kp);                                          \
        N01 = *(const bf16x8*)(kp + 1024);                                   \
        N10 = *(const bf16x8*)(kp + 2048);                                   \
        N11 = *(const bf16x8*)(kp + 3072);                                   \
        vp += 4096; kp += 4096;                                              \
        const f32x4 zero = (f32x4){0.f, 0.f, 0.f, 0.f};                      \
        _Pragma("unroll")                                                    \
        for (int u = 0; u < 2; ++u) {                                        \
            f32x4 s0 = mfma16(K00, qf32[u][0], zero);                        \
            s0       = mfma16(K01, qf32[u][1], s0);                          \
            f32x4 s1 = mfma16(K10, qf32[u][0], zero);                        \
            s1       = mfma16(K11, qf32[u][1], s1);                          \
            union { bf16x4 v; s16x4 s; } pf0, pf1;                           \
            _Pragma("unroll")                                                \
            for (int r = 0; r < 4; ++r) {                                    \
                float p0 = __builtin_amdgcn_exp2f(s0[r]);                    \
                float p1 = __builtin_amdgcn_exp2f(s1[r]);                    \
                lp[u] += p0 + p1;                                            \
                pf0.v[r] = (__bf16)p0;                                       \
                pf1.v[r] = (__bf16)p1;                                       \
            }                                                                \
            of[u][0] = mfma1k(pf0.s, v00, of[u][0]);                         \
            of[u][0] = mfma1k(pf1.s, v10, of[u][0]);                         \
            of[u][1] = mfma1k(pf0.s, v01, of[u][1]);                         \
            of[u][1] = mfma1k(pf1.s, v11, of[u][1]);                         \
            of[u][2] = mfma1k(pf0.s, v02, of[u][2]);                         \
            of[u][2] = mfma1k(pf1.s, v12, of[u][2]);                         \
            of[u][3] = mfma1k(pf0.s, v03, of[u][3]);                         \
            of[u][3] = mfma1k(pf1.s, v13, of[u][3]);                         \
        }                                                                    \
    } while (0)

__global__ __launch_bounds__(256, 4) void attn_kernel(
    const __hip_bfloat16* __restrict__ qbf,
    const __hip_bfloat16* __restrict__ kbf,
    const __hip_bfloat16* __restrict__ vbf,
    float* __restrict__ Oacc, float* __restrict__ lacc,
    float* __restrict__ outz)
{
    if (blockIdx.x == 0) {
        #pragma unroll
        for (int z = 0; z < 4; ++z)
            ((float4*)outz)[threadIdx.x * 4 + z] = (float4){0.f, 0.f, 0.f, 0.f};
    }

    const int qb    = blockIdx.x >> 4;
    const int bg    = blockIdx.x & 15;
    const int w     = threadIdx.x >> 6;
    const int lane  = threadIdx.x & 63;
    const int l16   = lane & 15;
    const int quad  = lane >> 4;
    const int r0    = qb * 128 + w * 32;
    const int fo    = l16 * 16 + quad * 4;            // K=16 frag elem offset
    const int fo32  = l16 * 16 + (quad & 1) * 8;      // K=32 frag elem offset
    const int qh    = quad >> 1;                      // K=32 tile-pair half

    // Q fragments in K=32 form
    bf16x8 qf32[2][2];
    #pragma unroll
    for (int u = 0; u < 2; ++u)
        #pragma unroll
        for (int p = 0; p < 2; ++p)
            qf32[u][p] = *(const bf16x8*)(qbf +
                ((((r0 >> 4) + u) * 4 + p * 2 + qh) << 8) + fo32);

    f32x4 of[2][4];
    float lp[2] = {0.f, 0.f};
    #pragma unroll
    for (int u = 0; u < 2; ++u)
        #pragma unroll
        for (int n = 0; n < 4; ++n)
            of[u][n] = (f32x4){0.f, 0.f, 0.f, 0.f};

    // byte pointers: chunk stride 2048 B, iteration (2 chunks) stride 4096 B
    const int ck0 = bg * 32;                          // 32 chunks = 512 keys
    const char* kp = (const char*)kbf + ck0 * 2048 + qh * 512 + fo32 * 2;
    const char* vp = (const char*)vbf + ck0 * 2048 + fo * 2;

    bf16x8 kA00, kA01, kA10, kA11, kB00, kB01, kB10, kB11;
    kA00 = *(const bf16x8*)(kp);
    kA01 = *(const bf16x8*)(kp + 1024);
    kA10 = *(const bf16x8*)(kp + 2048);
    kA11 = *(const bf16x8*)(kp + 3072);
    kp += 4096;

    #pragma unroll 1
    for (int body = 0; body < 8; ++body) {
        ATTN_ITER(kA00, kA01, kA10, kA11, kB00, kB01, kB10, kB11);
        ATTN_ITER(kB00, kB01, kB10, kB11, kA00, kA01, kA10, kA11);
    }

    // per-wave l reduction across quads
    #pragma unroll
    for (int u = 0; u < 2; ++u) {
        float v = lp[u];
        v += __shfl_xor(v, 16, 64);
        v += __shfl_xor(v, 32, 64);
        lp[u] = v;
    }

    // atomic accumulation: rows [r0, r0+32) of Oacc / lacc
    #pragma unroll
    for (int u = 0; u < 2; ++u)
        #pragma unroll
        for (int n = 0; n < 4; ++n)
            #pragma unroll
            for (int r = 0; r < 4; ++r)
                atomicAdd(&Oacc[(size_t)(r0 + u * 16 + quad * 4 + r) * 64 + n * 16 + l16],
                          of[u][n][r]);
    if (quad == 0) {
        atomicAdd(&lacc[r0 + l16],      lp[0]);
        atomicAdd(&lacc[r0 + 16 + l16], lp[1]);
    }
}

// ---------------------------------------------------------------------------
// Kernel 3: fused normalize + sim GEMM. grid = 32 blocks x 256 thr.
// Block bk covers k-range [bk*256, bk*256+256) of the 8192-long contraction
// (k = a*64 + d) -> needs exactly the 256 rows {(b, a0+j) : b<64, j<4},
// a0 = bk*4. Phase 1: normalize those rows (divide by lacc, l2-normalize)
// into LDS (row stride padded to 264 bf16 -> 2-way banks, free). Phase 2:
// split-K MFMA GEMM vs vnb, atomicAdd into out.
__global__ __launch_bounds__(256) void sim_kernel(
    const __hip_bfloat16* __restrict__ vnb,
    const float* __restrict__ Oacc, const float* __restrict__ lacc,
    float* __restrict__ out)
{
    __shared__ __hip_bfloat16 qn[64][264];

    const int a0 = blockIdx.x * 4;
    // ---- phase 1: thread i normalizes row (b = i>>2, a = a0 + (i&3)) ----
    {
        const int i   = threadIdx.x;
        const int b   = i >> 2, j = i & 3;
        const int row = b * 128 + a0 + j;
        const float4* Or = (const float4*)(Oacc + (size_t)row * 64);
        const float inv_l = 1.0f / lacc[row];
        float4 v[16];
        float ss = 0.f;
        #pragma unroll
        for (int c4 = 0; c4 < 16; ++c4) {
            float4 t = Or[c4];
            t.x *= inv_l; t.y *= inv_l; t.z *= inv_l; t.w *= inv_l;
            ss += t.x * t.x + t.y * t.y + t.z * t.z + t.w * t.w;
            v[c4] = t;
        }
        const float inv = rsqrtf(fmaxf(ss, 1e-24f));
        #pragma unroll
        for (int c4 = 0; c4 < 16; ++c4) {
            v[c4].x *= inv; v[c4].y *= inv; v[c4].z *= inv; v[c4].w *= inv;
        }
        #pragma unroll
        for (int m = 0; m < 8; ++m)
            *(bf16x8*)&qn[b][j * 64 + m * 8] = cvt8(v[2 * m], v[2 * m + 1]);
    }
    __syncthreads();

    // ---- phase 2: GEMM. 4 waves x 2 k-slices of this block's 256-k range --
    const int w    = threadIdx.x >> 6;
    const int lane = threadIdx.x & 63;
    const int l16  = lane & 15;
    const int quad = lane >> 4;
    const int kblk = blockIdx.x * 256;

    f32x4 acc[4][4];
    #pragma unroll
    for (int mi = 0; mi < 4; ++mi)
        #pragma unroll
        for (int ni = 0; ni < 4; ++ni)
            acc[mi][ni] = (f32x4){0.f, 0.f, 0.f, 0.f};

    #pragma unroll
    for (int s = 0; s < 2; ++s) {
        const int k0 = (w * 2 + s) * 32 + quad * 8;   // local k in [0,256)
        bf16x8 af[4], bfv[4];
        #pragma unroll
        for (int mi = 0; mi < 4; ++mi)
            af[mi] = *(const bf16x8*)(vnb + (size_t)(mi * 16 + l16) * 8192 + kblk + k0);
        #pragma unroll
        for (int ni = 0; ni < 4; ++ni)
            bfv[ni] = *(const bf16x8*)&qn[ni * 16 + l16][k0];
        #pragma unroll
        for (int mi = 0; mi < 4; ++mi)
            #pragma unroll
            for (int ni = 0; ni < 4; ++ni)
                acc[mi][ni] = mfma16(af[mi], bfv[ni], acc[mi][ni]);
    }

    #pragma unroll
    for (int mi = 0; mi < 4; ++mi)
        #pragma unroll
        for (int ni = 0; ni < 4; ++ni)
            #pragma unroll
            for (int r = 0; r < 4; ++r)
                atomicAdd(&out[(mi * 16 + quad * 4 + r) * 64 + ni * 16 + l16],
                          acc[mi][ni][r] * (1.f / 128.f));
}

// ---------------------------------------------------------------------------
extern "C" void kernel_launch(void* const* d_in, const int* in_sizes, int n_in,
                              void* d_out, int out_size, void* d_ws, size_t ws_size,
                              hipStream_t stream)
{
    const float* feat = (const float*)d_in[0];
    const float* Wq   = (const float*)d_in[1];
    const float* bq   = (const float*)d_in[2];
    const float* Wk   = (const float*)d_in[3];
    const float* bk   = (const float*)d_in[4];
    const float* Wv   = (const float*)d_in[5];
    const float* bv   = (const float*)d_in[6];
    float* out = (float*)d_out;

    const size_t MB = 1u << 20;
    char* ws = (char*)d_ws;
    __hip_bfloat16* qbf = (__hip_bfloat16*)(ws);              // 1 MB (frag-tiled, pre-scaled)
    __hip_bfloat16* kbf = (__hip_bfloat16*)(ws + 1 * MB);     // 1 MB (frag-tiled)
    __hip_bfloat16* vbf = (__hip_bfloat16*)(ws + 2 * MB);     // 1 MB (frag-tiled)
    __hip_bfloat16* vnb = (__hip_bfloat16*)(ws + 3 * MB);     // 1 MB (row-major)
    float* Oacc = (float*)(ws + 4 * MB);                      // 2 MB (8192 x 64 f32)
    float* lacc = (float*)(ws + 6 * MB);                      // 32 KB (8192 f32), contiguous after Oacc

    proj_kernel<<<768, 256, 0, stream>>>(feat, Wq, bq, Wk, bk, Wv, bv,
                                         qbf, kbf, vbf, vnb, Oacc);
    attn_kernel<<<1024, 256, 0, stream>>>(qbf, kbf, vbf, Oacc, lacc, out);
    sim_kernel<<<32, 256, 0, stream>>>(vnb, Oacc, lacc, out);
}

// Round 4
// 133.424 us; speedup vs baseline: 1.0124x; 1.0077x over previous
//
#include <hip/hip_runtime.h>
#include <hip/hip_bf16.h>

#define NROW 8192   // B*A = 64*128
#define INC  128
#define OUTC 64
#define BG   16     // key-split factor: grid 1024

// Q is pre-scaled by log2(e)/sqrt(64) at projection time, so attention
// computes p = exp2(q'.k) with a single v_exp_f32 per score.
#define QSCALE 0.18033688011112042f

typedef __bf16 bf16x8 __attribute__((ext_vector_type(8)));
typedef __bf16 bf16x4 __attribute__((ext_vector_type(4)));
typedef short  s16x4  __attribute__((ext_vector_type(4)));
typedef float  f32x4  __attribute__((ext_vector_type(4)));

static __device__ __forceinline__ f32x4 mfma16(bf16x8 a, bf16x8 b, f32x4 c) {
    return __builtin_amdgcn_mfma_f32_16x16x32_bf16(a, b, c, 0, 0, 0);
}
// 16x16x16 bf16 (K=16). C/D of S^T IS the A-operand layout of P for PV.
static __device__ __forceinline__ f32x4 mfma1k(s16x4 a, s16x4 b, f32x4 c) {
    return __builtin_amdgcn_mfma_f32_16x16x16bf16_1k(a, b, c, 0, 0, 0);
}

static __device__ __forceinline__ bf16x8 cvt8(float4 lo, float4 hi) {
    bf16x8 r;
    r[0] = (__bf16)lo.x; r[1] = (__bf16)lo.y; r[2] = (__bf16)lo.z; r[3] = (__bf16)lo.w;
    r[4] = (__bf16)hi.x; r[5] = (__bf16)hi.y; r[6] = (__bf16)hi.z; r[7] = (__bf16)hi.w;
    return r;
}

// ---------------------------------------------------------------------------
// Kernel 1: projection via MFMA. grid = 768 = mat(3) x b(64) x aq(4).
// Q/K/V written in FRAGMENT-TILED layout (512-B 16x16 tiles), Q pre-scaled.
// Also zeroes the Oacc/lacc accumulators (graph dependency orders this
// before attn's atomics) -> no separate memset dispatch.
__global__ __launch_bounds__(256) void proj_kernel(
    const float* __restrict__ feat,
    const float* __restrict__ Wq, const float* __restrict__ bq,
    const float* __restrict__ Wk, const float* __restrict__ bk,
    const float* __restrict__ Wv, const float* __restrict__ bv,
    __hip_bfloat16* __restrict__ qbf, __hip_bfloat16* __restrict__ kbf,
    __hip_bfloat16* __restrict__ vbf, __hip_bfloat16* __restrict__ vnb,
    float* __restrict__ Oacc /* 2MB Oacc + 32KB lacc, contiguous */)
{
    __shared__ float slab[32 * 132];
    __shared__ float vbuf[32 * 66];
    __shared__ float invb[32];

    const int blk = blockIdx.x;

    // zero Oacc (8192x64 f32) + lacc (8192 f32) = 133120 float4s
    {
        const int zi = blk * 256 + threadIdx.x;
        if (zi < 133120)
            ((float4*)Oacc)[zi] = (float4){0.f, 0.f, 0.f, 0.f};
    }

    const int mat = blk >> 8;
    const int b   = (blk >> 2) & 63;
    const int a0  = (blk & 3) * 32;
    const int r0  = b * 128 + a0;
    const float* fb = feat + (size_t)b * INC * 128;

    for (int i = threadIdx.x; i < 32 * 128; i += 256) {
        int c = i >> 5, a = i & 31;
        slab[a * 132 + c] = fb[c * 128 + a0 + a];
    }
    __syncthreads();

    const int w    = threadIdx.x >> 6;
    const int lane = threadIdx.x & 63;
    const int l16  = lane & 15;
    const int quad = lane >> 4;
    const int n0   = w * 16;

    const float* W    = (mat == 0) ? Wq : (mat == 1) ? Wk : Wv;
    const float* bias = (mat == 0) ? bq : (mat == 1) ? bk : bv;

    f32x4 acc[2] = {{0.f,0.f,0.f,0.f},{0.f,0.f,0.f,0.f}};
    #pragma unroll
    for (int kc = 0; kc < 4; ++kc) {
        const int k0 = kc * 32 + quad * 8;
        const float* wr = W + (n0 + l16) * INC + k0;
        bf16x8 bfr = cvt8(*(const float4*)wr, *(const float4*)(wr + 4));
        #pragma unroll
        for (int u = 0; u < 2; ++u) {
            const float* ar = slab + (u * 16 + l16) * 132 + k0;
            bf16x8 afr = cvt8(*(const float4*)ar, *(const float4*)(ar + 4));
            acc[u] = mfma16(afr, bfr, acc[u]);
        }
    }
    const float bl = bias[n0 + l16];
    const float sc = (mat == 0) ? QSCALE : 1.0f;

    if (mat < 2) {
        __hip_bfloat16* dst = mat ? kbf : qbf;
        #pragma unroll
        for (int u = 0; u < 2; ++u) {
            const int base = ((((r0 >> 4) + u) * 4 + w) << 8) + l16;
            #pragma unroll
            for (int r = 0; r < 4; ++r)
                dst[base + (quad * 4 + r) * 16] = __float2bfloat16((acc[u][r] + bl) * sc);
        }
    } else {
        #pragma unroll
        for (int u = 0; u < 2; ++u)
            #pragma unroll
            for (int r = 0; r < 4; ++r)
                vbuf[(u * 16 + quad * 4 + r) * 66 + n0 + l16] = acc[u][r] + bl;
        __syncthreads();
        const int rl = threadIdx.x >> 3;
        const int jj = threadIdx.x & 7;
        float ss = 0.f;
        #pragma unroll
        for (int i = 0; i < 8; ++i) {
            float x = vbuf[rl * 66 + jj * 8 + i];
            ss += x * x;
        }
        ss += __shfl_xor(ss, 1, 64);
        ss += __shfl_xor(ss, 2, 64);
        ss += __shfl_xor(ss, 4, 64);
        if (jj == 0) invb[rl] = rsqrtf(fmaxf(ss, 1e-24f));
        __syncthreads();
        float inv = invb[rl];
        bf16x8 vp;
        #pragma unroll
        for (int i = 0; i < 8; ++i)
            vp[i] = (__bf16)(vbuf[rl * 66 + jj * 8 + i] * inv);
        *(bf16x8*)(vnb + (size_t)(r0 + rl) * 64 + jj * 8) = vp;
        const int tl = threadIdx.x & 15;
        const int n  = (threadIdx.x >> 4) & 3;
        const int s_ = threadIdx.x >> 6;
        bf16x8 pack;
        #pragma unroll
        for (int j = 0; j < 8; ++j) {
            int key = s_ * 8 + j;
            pack[j] = (__bf16)(vbuf[key * 66 + n * 16 + tl] * invb[key]);
        }
        const int base = ((((r0 >> 4) + (s_ >> 1)) * 4 + n) << 8) + tl * 16 + (s_ & 1) * 8;
        *(bf16x8*)(vbf + base) = pack;
    }
}

// ---------------------------------------------------------------------------
// Kernel 2: attention. grid = 1024 = qb(64) x bg(16); block = 128 q-rows x
// 512 keys.
//
// ROUND 4: __launch_bounds__(256, 4) capped the unified VGPR+AGPR budget at
// 128/wave while the live set is ~130-156 (of=32 accum, K dbuf=32, Q=16,
// V=16, temps) -> compiler kept only 56 arch VGPRs and cycled the rest
// through scratch (~840MB L2 spill traffic ~= 40us of the 55us runtime,
// VALUBusy 3x the visible instruction stream). Hardware was delivering only
// ~3 blocks/CU anyway (Occupancy 30%). (256, 3) lifts the cap to ~170:
// zero spill at the SAME residency.
#define ATTN_ITER(K00,K01,K10,K11, N00,N01,N10,N11)                          \
    do {                                                                     \
        s16x4 v00 = *(const s16x4*)(vp);                                     \
        s16x4 v01 = *(const s16x4*)(vp + 512);                               \
        s16x4 v02 = *(const s16x4*)(vp + 1024);                              \
        s16x4 v03 = *(const s16x4*)(vp + 1536);                              \
        s16x4 v10 = *(const s16x4*)(vp + 2048);                              \
        s16x4 v11 = *(const s16x4*)(vp + 2560);                              \
        s16x4 v12 = *(const s16x4*)(vp + 3072);                              \
        s16x4 v13 = *(const s16x4*)(vp + 3584);                              \
        N00 = *(const bf16x8*)(kp);                                          \
        N01 = *(const bf16x8*)(kp + 1024);                                   \
        N10 = *(const bf16x8*)(kp + 2048);                                   \
        N11 = *(const bf16x8*)(kp + 3072);                                   \
        vp += 4096; kp += 4096;                                              \
        const f32x4 zero = (f32x4){0.f, 0.f, 0.f, 0.f};                      \
        _Pragma("unroll")                                                    \
        for (int u = 0; u < 2; ++u) {                                        \
            f32x4 s0 = mfma16(K00, qf32[u][0], zero);                        \
            s0       = mfma16(K01, qf32[u][1], s0);                          \
            f32x4 s1 = mfma16(K10, qf32[u][0], zero);                        \
            s1       = mfma16(K11, qf32[u][1], s1);                          \
            union { bf16x4 v; s16x4 s; } pf0, pf1;                           \
            _Pragma("unroll")                                                \
            for (int r = 0; r < 4; ++r) {                                    \
                float p0 = __builtin_amdgcn_exp2f(s0[r]);                    \
                float p1 = __builtin_amdgcn_exp2f(s1[r]);                    \
                lp[u] += p0 + p1;                                            \
                pf0.v[r] = (__bf16)p0;                                       \
                pf1.v[r] = (__bf16)p1;                                       \
            }                                                                \
            of[u][0] = mfma1k(pf0.s, v00, of[u][0]);                         \
            of[u][0] = mfma1k(pf1.s, v10, of[u][0]);                         \
            of[u][1] = mfma1k(pf0.s, v01, of[u][1]);                         \
            of[u][1] = mfma1k(pf1.s, v11, of[u][1]);                         \
            of[u][2] = mfma1k(pf0.s, v02, of[u][2]);                         \
            of[u][2] = mfma1k(pf1.s, v12, of[u][2]);                         \
            of[u][3] = mfma1k(pf0.s, v03, of[u][3]);                         \
            of[u][3] = mfma1k(pf1.s, v13, of[u][3]);                         \
        }                                                                    \
    } while (0)

__global__ __launch_bounds__(256, 3) void attn_kernel(
    const __hip_bfloat16* __restrict__ qbf,
    const __hip_bfloat16* __restrict__ kbf,
    const __hip_bfloat16* __restrict__ vbf,
    float* __restrict__ Oacc, float* __restrict__ lacc,
    float* __restrict__ outz)
{
    if (blockIdx.x == 0) {
        #pragma unroll
        for (int z = 0; z < 4; ++z)
            ((float4*)outz)[threadIdx.x * 4 + z] = (float4){0.f, 0.f, 0.f, 0.f};
    }

    const int qb    = blockIdx.x >> 4;
    const int bg    = blockIdx.x & 15;
    const int w     = threadIdx.x >> 6;
    const int lane  = threadIdx.x & 63;
    const int l16   = lane & 15;
    const int quad  = lane >> 4;
    const int r0    = qb * 128 + w * 32;
    const int fo    = l16 * 16 + quad * 4;            // K=16 frag elem offset
    const int fo32  = l16 * 16 + (quad & 1) * 8;      // K=32 frag elem offset
    const int qh    = quad >> 1;                      // K=32 tile-pair half

    // Q fragments in K=32 form
    bf16x8 qf32[2][2];
    #pragma unroll
    for (int u = 0; u < 2; ++u)
        #pragma unroll
        for (int p = 0; p < 2; ++p)
            qf32[u][p] = *(const bf16x8*)(qbf +
                ((((r0 >> 4) + u) * 4 + p * 2 + qh) << 8) + fo32);

    f32x4 of[2][4];
    float lp[2] = {0.f, 0.f};
    #pragma unroll
    for (int u = 0; u < 2; ++u)
        #pragma unroll
        for (int n = 0; n < 4; ++n)
            of[u][n] = (f32x4){0.f, 0.f, 0.f, 0.f};

    // byte pointers: chunk stride 2048 B, iteration (2 chunks) stride 4096 B
    const int ck0 = bg * 32;                          // 32 chunks = 512 keys
    const char* kp = (const char*)kbf + ck0 * 2048 + qh * 512 + fo32 * 2;
    const char* vp = (const char*)vbf + ck0 * 2048 + fo * 2;

    bf16x8 kA00, kA01, kA10, kA11, kB00, kB01, kB10, kB11;
    kA00 = *(const bf16x8*)(kp);
    kA01 = *(const bf16x8*)(kp + 1024);
    kA10 = *(const bf16x8*)(kp + 2048);
    kA11 = *(const bf16x8*)(kp + 3072);
    kp += 4096;

    #pragma unroll 1
    for (int body = 0; body < 8; ++body) {
        ATTN_ITER(kA00, kA01, kA10, kA11, kB00, kB01, kB10, kB11);
        ATTN_ITER(kB00, kB01, kB10, kB11, kA00, kA01, kA10, kA11);
    }

    // per-wave l reduction across quads
    #pragma unroll
    for (int u = 0; u < 2; ++u) {
        float v = lp[u];
        v += __shfl_xor(v, 16, 64);
        v += __shfl_xor(v, 32, 64);
        lp[u] = v;
    }

    // atomic accumulation: rows [r0, r0+32) of Oacc / lacc
    #pragma unroll
    for (int u = 0; u < 2; ++u)
        #pragma unroll
        for (int n = 0; n < 4; ++n)
            #pragma unroll
            for (int r = 0; r < 4; ++r)
                atomicAdd(&Oacc[(size_t)(r0 + u * 16 + quad * 4 + r) * 64 + n * 16 + l16],
                          of[u][n][r]);
    if (quad == 0) {
        atomicAdd(&lacc[r0 + l16],      lp[0]);
        atomicAdd(&lacc[r0 + 16 + l16], lp[1]);
    }
}

// ---------------------------------------------------------------------------
// Kernel 3: fused normalize + sim GEMM. grid = 32 blocks x 256 thr.
// Block bk covers k-range [bk*256, bk*256+256) of the 8192-long contraction
// (k = a*64 + d) -> needs exactly the 256 rows {(b, a0+j) : b<64, j<4},
// a0 = bk*4. Phase 1: normalize those rows (divide by lacc, l2-normalize)
// into LDS (row stride padded to 264 bf16 -> 2-way banks, free). Phase 2:
// split-K MFMA GEMM vs vnb, atomicAdd into out.
__global__ __launch_bounds__(256) void sim_kernel(
    const __hip_bfloat16* __restrict__ vnb,
    const float* __restrict__ Oacc, const float* __restrict__ lacc,
    float* __restrict__ out)
{
    __shared__ __hip_bfloat16 qn[64][264];

    const int a0 = blockIdx.x * 4;
    // ---- phase 1: thread i normalizes row (b = i>>2, a = a0 + (i&3)) ----
    {
        const int i   = threadIdx.x;
        const int b   = i >> 2, j = i & 3;
        const int row = b * 128 + a0 + j;
        const float4* Or = (const float4*)(Oacc + (size_t)row * 64);
        const float inv_l = 1.0f / lacc[row];
        float4 v[16];
        float ss = 0.f;
        #pragma unroll
        for (int c4 = 0; c4 < 16; ++c4) {
            float4 t = Or[c4];
            t.x *= inv_l; t.y *= inv_l; t.z *= inv_l; t.w *= inv_l;
            ss += t.x * t.x + t.y * t.y + t.z * t.z + t.w * t.w;
            v[c4] = t;
        }
        const float inv = rsqrtf(fmaxf(ss, 1e-24f));
        #pragma unroll
        for (int c4 = 0; c4 < 16; ++c4) {
            v[c4].x *= inv; v[c4].y *= inv; v[c4].z *= inv; v[c4].w *= inv;
        }
        #pragma unroll
        for (int m = 0; m < 8; ++m)
            *(bf16x8*)&qn[b][j * 64 + m * 8] = cvt8(v[2 * m], v[2 * m + 1]);
    }
    __syncthreads();

    // ---- phase 2: GEMM. 4 waves x 2 k-slices of this block's 256-k range --
    const int w    = threadIdx.x >> 6;
    const int lane = threadIdx.x & 63;
    const int l16  = lane & 15;
    const int quad = lane >> 4;
    const int kblk = blockIdx.x * 256;

    f32x4 acc[4][4];
    #pragma unroll
    for (int mi = 0; mi < 4; ++mi)
        #pragma unroll
        for (int ni = 0; ni < 4; ++ni)
            acc[mi][ni] = (f32x4){0.f, 0.f, 0.f, 0.f};

    #pragma unroll
    for (int s = 0; s < 2; ++s) {
        const int k0 = (w * 2 + s) * 32 + quad * 8;   // local k in [0,256)
        bf16x8 af[4], bfv[4];
        #pragma unroll
        for (int mi = 0; mi < 4; ++mi)
            af[mi] = *(const bf16x8*)(vnb + (size_t)(mi * 16 + l16) * 8192 + kblk + k0);
        #pragma unroll
        for (int ni = 0; ni < 4; ++ni)
            bfv[ni] = *(const bf16x8*)&qn[ni * 16 + l16][k0];
        #pragma unroll
        for (int mi = 0; mi < 4; ++mi)
            #pragma unroll
            for (int ni = 0; ni < 4; ++ni)
                acc[mi][ni] = mfma16(af[mi], bfv[ni], acc[mi][ni]);
    }

    #pragma unroll
    for (int mi = 0; mi < 4; ++mi)
        #pragma unroll
        for (int ni = 0; ni < 4; ++ni)
            #pragma unroll
            for (int r = 0; r < 4; ++r)
                atomicAdd(&out[(mi * 16 + quad * 4 + r) * 64 + ni * 16 + l16],
                          acc[mi][ni][r] * (1.f / 128.f));
}

// ---------------------------------------------------------------------------
extern "C" void kernel_launch(void* const* d_in, const int* in_sizes, int n_in,
                              void* d_out, int out_size, void* d_ws, size_t ws_size,
                              hipStream_t stream)
{
    const float* feat = (const float*)d_in[0];
    const float* Wq   = (const float*)d_in[1];
    const float* bq   = (const float*)d_in[2];
    const float* Wk   = (const float*)d_in[3];
    const float* bk   = (const float*)d_in[4];
    const float* Wv   = (const float*)d_in[5];
    const float* bv   = (const float*)d_in[6];
    float* out = (float*)d_out;

    const size_t MB = 1u << 20;
    char* ws = (char*)d_ws;
    __hip_bfloat16* qbf = (__hip_bfloat16*)(ws);              // 1 MB (frag-tiled, pre-scaled)
    __hip_bfloat16* kbf = (__hip_bfloat16*)(ws + 1 * MB);     // 1 MB (frag-tiled)
    __hip_bfloat16* vbf = (__hip_bfloat16*)(ws + 2 * MB);     // 1 MB (frag-tiled)
    __hip_bfloat16* vnb = (__hip_bfloat16*)(ws + 3 * MB);     // 1 MB (row-major)
    float* Oacc = (float*)(ws + 4 * MB);                      // 2 MB (8192 x 64 f32)
    float* lacc = (float*)(ws + 6 * MB);                      // 32 KB (8192 f32), contiguous after Oacc

    proj_kernel<<<768, 256, 0, stream>>>(feat, Wq, bq, Wk, bk, Wv, bv,
                                         qbf, kbf, vbf, vnb, Oacc);
    attn_kernel<<<1024, 256, 0, stream>>>(qbf, kbf, vbf, Oacc, lacc, out);
    sim_kernel<<<32, 256, 0, stream>>>(vnb, Oacc, lacc, out);
}

// Round 5
// 119.013 us; speedup vs baseline: 1.1350x; 1.1211x over previous
//
#include <hip/hip_runtime.h>
#include <hip/hip_bf16.h>

#define NROW 8192   // B*A = 64*128
#define INC  128
#define OUTC 64
#define BG   16     // key-split factor

// Q is pre-scaled by log2(e)/sqrt(64) at projection time, so attention
// computes p = exp2(q'.k) with a single v_exp_f32 per score.
#define QSCALE 0.18033688011112042f

typedef __bf16 bf16x8 __attribute__((ext_vector_type(8)));
typedef __bf16 bf16x4 __attribute__((ext_vector_type(4)));
typedef short  s16x4  __attribute__((ext_vector_type(4)));
typedef float  f32x4  __attribute__((ext_vector_type(4)));

static __device__ __forceinline__ f32x4 mfma16(bf16x8 a, bf16x8 b, f32x4 c) {
    return __builtin_amdgcn_mfma_f32_16x16x32_bf16(a, b, c, 0, 0, 0);
}
// 16x16x16 bf16 (K=16). C/D of S^T IS the A-operand layout of P for PV.
static __device__ __forceinline__ f32x4 mfma1k(s16x4 a, s16x4 b, f32x4 c) {
    return __builtin_amdgcn_mfma_f32_16x16x16bf16_1k(a, b, c, 0, 0, 0);
}

static __device__ __forceinline__ bf16x8 cvt8(float4 lo, float4 hi) {
    bf16x8 r;
    r[0] = (__bf16)lo.x; r[1] = (__bf16)lo.y; r[2] = (__bf16)lo.z; r[3] = (__bf16)lo.w;
    r[4] = (__bf16)hi.x; r[5] = (__bf16)hi.y; r[6] = (__bf16)hi.z; r[7] = (__bf16)hi.w;
    return r;
}

// ---------------------------------------------------------------------------
// Kernel 1: projection via MFMA. grid = 768 = mat(3) x b(64) x aq(4).
// Q/K/V written in FRAGMENT-TILED layout (512-B 16x16 tiles), Q pre-scaled.
__global__ __launch_bounds__(256) void proj_kernel(
    const float* __restrict__ feat,
    const float* __restrict__ Wq, const float* __restrict__ bq,
    const float* __restrict__ Wk, const float* __restrict__ bk,
    const float* __restrict__ Wv, const float* __restrict__ bv,
    __hip_bfloat16* __restrict__ qbf, __hip_bfloat16* __restrict__ kbf,
    __hip_bfloat16* __restrict__ vbf, __hip_bfloat16* __restrict__ vnb)
{
    __shared__ float slab[32 * 132];
    __shared__ float vbuf[32 * 66];
    __shared__ float invb[32];

    const int blk = blockIdx.x;
    const int mat = blk >> 8;
    const int b   = (blk >> 2) & 63;
    const int a0  = (blk & 3) * 32;
    const int r0  = b * 128 + a0;
    const float* fb = feat + (size_t)b * INC * 128;

    for (int i = threadIdx.x; i < 32 * 128; i += 256) {
        int c = i >> 5, a = i & 31;
        slab[a * 132 + c] = fb[c * 128 + a0 + a];
    }
    __syncthreads();

    const int w    = threadIdx.x >> 6;
    const int lane = threadIdx.x & 63;
    const int l16  = lane & 15;
    const int quad = lane >> 4;
    const int n0   = w * 16;

    const float* W    = (mat == 0) ? Wq : (mat == 1) ? Wk : Wv;
    const float* bias = (mat == 0) ? bq : (mat == 1) ? bk : bv;

    f32x4 acc[2] = {{0.f,0.f,0.f,0.f},{0.f,0.f,0.f,0.f}};
    #pragma unroll
    for (int kc = 0; kc < 4; ++kc) {
        const int k0 = kc * 32 + quad * 8;
        const float* wr = W + (n0 + l16) * INC + k0;
        bf16x8 bfr = cvt8(*(const float4*)wr, *(const float4*)(wr + 4));
        #pragma unroll
        for (int u = 0; u < 2; ++u) {
            const float* ar = slab + (u * 16 + l16) * 132 + k0;
            bf16x8 afr = cvt8(*(const float4*)ar, *(const float4*)(ar + 4));
            acc[u] = mfma16(afr, bfr, acc[u]);
        }
    }
    const float bl = bias[n0 + l16];
    const float sc = (mat == 0) ? QSCALE : 1.0f;

    if (mat < 2) {
        __hip_bfloat16* dst = mat ? kbf : qbf;
        #pragma unroll
        for (int u = 0; u < 2; ++u) {
            const int base = ((((r0 >> 4) + u) * 4 + w) << 8) + l16;
            #pragma unroll
            for (int r = 0; r < 4; ++r)
                dst[base + (quad * 4 + r) * 16] = __float2bfloat16((acc[u][r] + bl) * sc);
        }
    } else {
        #pragma unroll
        for (int u = 0; u < 2; ++u)
            #pragma unroll
            for (int r = 0; r < 4; ++r)
                vbuf[(u * 16 + quad * 4 + r) * 66 + n0 + l16] = acc[u][r] + bl;
        __syncthreads();
        const int rl = threadIdx.x >> 3;
        const int jj = threadIdx.x & 7;
        float ss = 0.f;
        #pragma unroll
        for (int i = 0; i < 8; ++i) {
            float x = vbuf[rl * 66 + jj * 8 + i];
            ss += x * x;
        }
        ss += __shfl_xor(ss, 1, 64);
        ss += __shfl_xor(ss, 2, 64);
        ss += __shfl_xor(ss, 4, 64);
        if (jj == 0) invb[rl] = rsqrtf(fmaxf(ss, 1e-24f));
        __syncthreads();
        float inv = invb[rl];
        bf16x8 vp;
        #pragma unroll
        for (int i = 0; i < 8; ++i)
            vp[i] = (__bf16)(vbuf[rl * 66 + jj * 8 + i] * inv);
        *(bf16x8*)(vnb + (size_t)(r0 + rl) * 64 + jj * 8) = vp;
        const int tl = threadIdx.x & 15;
        const int n  = (threadIdx.x >> 4) & 3;
        const int s_ = threadIdx.x >> 6;
        bf16x8 pack;
        #pragma unroll
        for (int j = 0; j < 8; ++j) {
            int key = s_ * 8 + j;
            pack[j] = (__bf16)(vbuf[key * 66 + n * 16 + tl] * invb[key]);
        }
        const int base = ((((r0 >> 4) + (s_ >> 1)) * 4 + n) << 8) + tl * 16 + (s_ & 1) * 8;
        *(bf16x8*)(vbf + base) = pack;
    }
}

// ---------------------------------------------------------------------------
// Kernel 2: attention. grid = 512 = qb(32) x bg(16); block = 256 q-rows x
// 512 keys; exactly 2 blocks/CU, whole grid resident in one shot.
//
// ROUND 5 theory: per-CU VMEM-instruction issue (TA) is the shared
// bottleneck (r0->r1 kept VMEM/CU constant and time was invariant; no pipe
// >19% busy; occupancy decodes to ~200 unified regs/wave - no spill, the
// VGPR_Count=56 is arch-VGPRs only). Fix: 64 q-rows per wave (of=16 f32x4)
// so each K/V load amortizes over 2x the MFMA work -> per-CU VMEM instrs
// halve (786k -> 393k). V is now double-buffered like K (load->use distance
// = full iteration). Epilogue reverts to STREAMING Opart/lpart stores
// (r2's 8.4M device-scope atomics all went memory-side RMW: +10-15us).
// Reg estimate: of 64 + qf 32 + Kdbuf 32 + Vdbuf 32 + temps ~30 = ~190
// unified < 256 cap from __launch_bounds__(256,2).
#define ATTN_ITER(K00,K01,K10,K11, NK00,NK01,NK10,NK11,                      \
                  V0,V1,V2,V3,V4,V5,V6,V7,                                   \
                  NV0,NV1,NV2,NV3,NV4,NV5,NV6,NV7)                           \
    do {                                                                     \
        NV0 = *(const s16x4*)(vp);                                           \
        NV1 = *(const s16x4*)(vp + 512);                                     \
        NV2 = *(const s16x4*)(vp + 1024);                                    \
        NV3 = *(const s16x4*)(vp + 1536);                                    \
        NV4 = *(const s16x4*)(vp + 2048);                                    \
        NV5 = *(const s16x4*)(vp + 2560);                                    \
        NV6 = *(const s16x4*)(vp + 3072);                                    \
        NV7 = *(const s16x4*)(vp + 3584);                                    \
        NK00 = *(const bf16x8*)(kp);                                         \
        NK01 = *(const bf16x8*)(kp + 1024);                                  \
        NK10 = *(const bf16x8*)(kp + 2048);                                  \
        NK11 = *(const bf16x8*)(kp + 3072);                                  \
        vp += 4096; kp += 4096;                                              \
        const f32x4 zero = (f32x4){0.f, 0.f, 0.f, 0.f};                      \
        _Pragma("unroll")                                                    \
        for (int u = 0; u < 4; ++u) {                                        \
            f32x4 s0 = mfma16(K00, qf32[u][0], zero);                        \
            s0       = mfma16(K01, qf32[u][1], s0);                          \
            f32x4 s1 = mfma16(K10, qf32[u][0], zero);                        \
            s1       = mfma16(K11, qf32[u][1], s1);                          \
            union { bf16x4 v; s16x4 s; } pf0, pf1;                           \
            _Pragma("unroll")                                                \
            for (int r = 0; r < 4; ++r) {                                    \
                float p0 = __builtin_amdgcn_exp2f(s0[r]);                    \
                float p1 = __builtin_amdgcn_exp2f(s1[r]);                    \
                lp[u] += p0 + p1;                                            \
                pf0.v[r] = (__bf16)p0;                                       \
                pf1.v[r] = (__bf16)p1;                                       \
            }                                                                \
            of[u][0] = mfma1k(pf0.s, V0, of[u][0]);                          \
            of[u][0] = mfma1k(pf1.s, V4, of[u][0]);                          \
            of[u][1] = mfma1k(pf0.s, V1, of[u][1]);                          \
            of[u][1] = mfma1k(pf1.s, V5, of[u][1]);                          \
            of[u][2] = mfma1k(pf0.s, V2, of[u][2]);                          \
            of[u][2] = mfma1k(pf1.s, V6, of[u][2]);                          \
            of[u][3] = mfma1k(pf0.s, V3, of[u][3]);                          \
            of[u][3] = mfma1k(pf1.s, V7, of[u][3]);                          \
        }                                                                    \
    } while (0)

__global__ __launch_bounds__(256, 2) void attn_kernel(
    const __hip_bfloat16* __restrict__ qbf,
    const __hip_bfloat16* __restrict__ kbf,
    const __hip_bfloat16* __restrict__ vbf,
    float* __restrict__ Opart, float* __restrict__ lpart)
{
    const int qb    = blockIdx.x >> 4;
    const int bg    = blockIdx.x & 15;
    const int w     = threadIdx.x >> 6;
    const int lane  = threadIdx.x & 63;
    const int l16   = lane & 15;
    const int quad  = lane >> 4;
    const int r0    = qb * 256 + w * 64;              // 64 q-rows per wave
    const int fo    = l16 * 16 + quad * 4;            // K=16 frag elem offset
    const int fo32  = l16 * 16 + (quad & 1) * 8;      // K=32 frag elem offset
    const int qh    = quad >> 1;                      // K=32 tile-pair half

    // Q fragments in K=32 form: 4 x 16-row subtiles
    bf16x8 qf32[4][2];
    #pragma unroll
    for (int u = 0; u < 4; ++u)
        #pragma unroll
        for (int p = 0; p < 2; ++p)
            qf32[u][p] = *(const bf16x8*)(qbf +
                ((((r0 >> 4) + u) * 4 + p * 2 + qh) << 8) + fo32);

    f32x4 of[4][4];
    float lp[4] = {0.f, 0.f, 0.f, 0.f};
    #pragma unroll
    for (int u = 0; u < 4; ++u)
        #pragma unroll
        for (int n = 0; n < 4; ++n)
            of[u][n] = (f32x4){0.f, 0.f, 0.f, 0.f};

    // byte pointers: chunk stride 2048 B, iteration (2 chunks) stride 4096 B
    const int ck0 = bg * 32;                          // 32 chunks = 512 keys
    const char* kp = (const char*)kbf + ck0 * 2048 + qh * 512 + fo32 * 2;
    const char* vp = (const char*)vbf + ck0 * 2048 + fo * 2;

    bf16x8 kA00, kA01, kA10, kA11, kB00, kB01, kB10, kB11;
    s16x4  vA0, vA1, vA2, vA3, vA4, vA5, vA6, vA7;
    s16x4  vB0, vB1, vB2, vB3, vB4, vB5, vB6, vB7;

    // prologue: load iteration 0's K and V
    vA0 = *(const s16x4*)(vp);
    vA1 = *(const s16x4*)(vp + 512);
    vA2 = *(const s16x4*)(vp + 1024);
    vA3 = *(const s16x4*)(vp + 1536);
    vA4 = *(const s16x4*)(vp + 2048);
    vA5 = *(const s16x4*)(vp + 2560);
    vA6 = *(const s16x4*)(vp + 3072);
    vA7 = *(const s16x4*)(vp + 3584);
    kA00 = *(const bf16x8*)(kp);
    kA01 = *(const bf16x8*)(kp + 1024);
    kA10 = *(const bf16x8*)(kp + 2048);
    kA11 = *(const bf16x8*)(kp + 3072);
    vp += 4096; kp += 4096;

    #pragma unroll 1
    for (int body = 0; body < 8; ++body) {
        ATTN_ITER(kA00, kA01, kA10, kA11, kB00, kB01, kB10, kB11,
                  vA0, vA1, vA2, vA3, vA4, vA5, vA6, vA7,
                  vB0, vB1, vB2, vB3, vB4, vB5, vB6, vB7);
        ATTN_ITER(kB00, kB01, kB10, kB11, kA00, kA01, kA10, kA11,
                  vB0, vB1, vB2, vB3, vB4, vB5, vB6, vB7,
                  vA0, vA1, vA2, vA3, vA4, vA5, vA6, vA7);
    }

    // per-wave l reduction across quads
    #pragma unroll
    for (int u = 0; u < 4; ++u) {
        float v = lp[u];
        v += __shfl_xor(v, 16, 64);
        v += __shfl_xor(v, 32, 64);
        lp[u] = v;
    }

    // streaming per-wave partial: tile = qb*4 + w owns rows [r0, r0+64)
    const int task = (qb * 4 + w) * 16 + bg;
    float* Ob = Opart + (size_t)task * 4096;
    #pragma unroll
    for (int u = 0; u < 4; ++u)
        #pragma unroll
        for (int n = 0; n < 4; ++n)
            #pragma unroll
            for (int r = 0; r < 4; ++r)
                Ob[(u * 16 + quad * 4 + r) * 64 + n * 16 + l16] = of[u][n][r];
    if (quad == 0) {
        #pragma unroll
        for (int u = 0; u < 4; ++u)
            lpart[task * 64 + u * 16 + l16] = lp[u];
    }
}

// ---------------------------------------------------------------------------
// Kernel 3: combine 16 partials/tile (64-row tiles), divide by l,
// l2-normalize -> qnb (bf16). grid = 2048 x 256 (full device).
__global__ __launch_bounds__(256) void combine_kernel(
    const float* __restrict__ Opart, const float* __restrict__ lpart,
    __hip_bfloat16* __restrict__ qnb)
{
    const int r    = blockIdx.x * 4 + (threadIdx.x >> 6);
    const int c    = threadIdx.x & 63;
    const int tile = r >> 6, row = r & 63;
    float acc = 0.f, lsum = 0.f;
    #pragma unroll
    for (int g = 0; g < 16; ++g) {
        int task = tile * 16 + g;
        acc  += Opart[(size_t)task * 4096 + row * 64 + c];
        lsum += lpart[task * 64 + row];
    }
    float q = acc / lsum;
    float ss = q * q;
    ss += __shfl_xor(ss, 1, 64);
    ss += __shfl_xor(ss, 2, 64);
    ss += __shfl_xor(ss, 4, 64);
    ss += __shfl_xor(ss, 8, 64);
    ss += __shfl_xor(ss, 16, 64);
    ss += __shfl_xor(ss, 32, 64);
    qnb[(size_t)r * 64 + c] = __float2bfloat16(q * rsqrtf(fmaxf(ss, 1e-24f)));
}

// ---------------------------------------------------------------------------
// Kernel 4: sim = (1/128) * Vn(64x8192) @ Qn(64x8192)^T, split-K MFMA GEMM.
// 256-thread blocks: 4 waves each take 2 of the 8 k-slices of this block's
// 256-key range; atomicAdd partials (4K distinct addresses).
__global__ __launch_bounds__(256) void sim_kernel(
    const __hip_bfloat16* __restrict__ vnb,
    const __hip_bfloat16* __restrict__ qnb,
    float* __restrict__ out)
{
    const int w    = threadIdx.x >> 6;
    const int lane = threadIdx.x & 63;
    const int l16  = lane & 15;
    const int quad = lane >> 4;
    const int kblk = blockIdx.x * 256;

    f32x4 acc[4][4];
    #pragma unroll
    for (int mi = 0; mi < 4; ++mi)
        #pragma unroll
        for (int ni = 0; ni < 4; ++ni)
            acc[mi][ni] = (f32x4){0.f, 0.f, 0.f, 0.f};

    #pragma unroll
    for (int s = 0; s < 2; ++s) {
        const int ks = w * 2 + s;
        const int k0 = kblk + ks * 32 + quad * 8;
        bf16x8 af[4], bfv[4];
        #pragma unroll
        for (int mi = 0; mi < 4; ++mi)
            af[mi] = *(const bf16x8*)(vnb + (size_t)(mi * 16 + l16) * 8192 + k0);
        #pragma unroll
        for (int ni = 0; ni < 4; ++ni)
            bfv[ni] = *(const bf16x8*)(qnb + (size_t)(ni * 16 + l16) * 8192 + k0);
        #pragma unroll
        for (int mi = 0; mi < 4; ++mi)
            #pragma unroll
            for (int ni = 0; ni < 4; ++ni)
                acc[mi][ni] = mfma16(af[mi], bfv[ni], acc[mi][ni]);
    }

    #pragma unroll
    for (int mi = 0; mi < 4; ++mi)
        #pragma unroll
        for (int ni = 0; ni < 4; ++ni)
            #pragma unroll
            for (int r = 0; r < 4; ++r)
                atomicAdd(&out[(mi * 16 + quad * 4 + r) * 64 + ni * 16 + l16],
                          acc[mi][ni][r] * (1.f / 128.f));
}

// ---------------------------------------------------------------------------
extern "C" void kernel_launch(void* const* d_in, const int* in_sizes, int n_in,
                              void* d_out, int out_size, void* d_ws, size_t ws_size,
                              hipStream_t stream)
{
    const float* feat = (const float*)d_in[0];
    const float* Wq   = (const float*)d_in[1];
    const float* bq   = (const float*)d_in[2];
    const float* Wk   = (const float*)d_in[3];
    const float* bk   = (const float*)d_in[4];
    const float* Wv   = (const float*)d_in[5];
    const float* bv   = (const float*)d_in[6];
    float* out = (float*)d_out;

    const size_t MB = 1u << 20;
    char* ws = (char*)d_ws;
    __hip_bfloat16* qbf = (__hip_bfloat16*)(ws);              // 1 MB (frag-tiled, pre-scaled)
    __hip_bfloat16* kbf = (__hip_bfloat16*)(ws + 1 * MB);     // 1 MB (frag-tiled)
    __hip_bfloat16* vbf = (__hip_bfloat16*)(ws + 2 * MB);     // 1 MB (frag-tiled)
    __hip_bfloat16* vnb = (__hip_bfloat16*)(ws + 3 * MB);     // 1 MB (row-major)
    float* Opart = (float*)(ws + 4 * MB);                     // 32 MB (2048 x 16 KB)
    float* lpart = (float*)(ws + 36 * MB);                    // 512 KB
    __hip_bfloat16* qnb = (__hip_bfloat16*)(ws + 37 * MB);    // 1 MB

    (void)hipMemsetAsync(out, 0, 64 * 64 * sizeof(float), stream);
    proj_kernel<<<768, 256, 0, stream>>>(feat, Wq, bq, Wk, bk, Wv, bv, qbf, kbf, vbf, vnb);
    attn_kernel<<<512, 256, 0, stream>>>(qbf, kbf, vbf, Opart, lpart);
    combine_kernel<<<2048, 256, 0, stream>>>(Opart, lpart, qnb);
    sim_kernel<<<32, 256, 0, stream>>>(vnb, qnb, out);
}